// Round 9
// baseline (107.502 us; speedup 1.0000x reference)
//
#include <hip/hip_runtime.h>
#include <hip/hip_bf16.h>

// EdgeConv forward, Round 9: FACTORED + int8-quantized gather target.
//   out[i] = relu(base_i + max_{j in N(i)} y_j)     (elementwise, DEG=16)
//   y      = X @ W2^T         -> int8 per-row-scaled (Y8 + scale), in ws
//   base   = bias + X @ (W1-W2)^T -> bf16, in ws
// Valid: max over edges is elementwise, base_i edge-invariant, relu monotone.
//
// R8 measurement: coalesced bf16 gather (6.4MB working set) is SERVICE-bound
// (~50% L2 miss at 4MB/XCD). R9 shrinks the gathered set to 3.4MB (i8+scale)
// -> fully L2-resident per XCD, bytes/edge halved. Quant error budget:
// i8 row-scale <=0.016 + bf16 base <=0.016 + bf16 MFMA 0.031 << 0.145.
//
// Fragment layouts (m89/m91-verified):
//   A[m=lane&15][k=(lane>>4)*8+j], B[k=(lane>>4)*8+j][n=lane&15],
//   D: col=lane&15, row=(lane>>4)*4+reg

#define DEG 16
#define C 64
#define WPB 4

typedef __attribute__((ext_vector_type(8))) short s16x8;
typedef __attribute__((ext_vector_type(4))) float f32x4;

__device__ __forceinline__ unsigned pk2(float lo, float hi) {
    __hip_bfloat162 h = __float22bfloat162_rn(make_float2(lo, hi));
    union { __hip_bfloat162 h; unsigned u; } c; c.h = h;
    return c.u;
}
__device__ __forceinline__ s16x8 cvt_frag(f32x4 a, f32x4 b) {
    union { unsigned u[4]; s16x8 v; } r;
    r.u[0] = pk2(a[0], a[1]); r.u[1] = pk2(a[2], a[3]);
    r.u[2] = pk2(b[0], b[1]); r.u[3] = pk2(b[2], b[3]);
    return r.v;
}
__device__ __forceinline__ float bf2f(unsigned short u) {
    union { unsigned u; float f; } c; c.u = ((unsigned)u) << 16;
    return c.f;
}

// ---- kernel 1: Y8/scale = quant(X@W2^T), Bb = bf16(bias + X@(W1-W2)^T) ----
// One wave per 16 rows; 16 MFMAs/wave; 3125 waves. N=50000 = 3125*16 (no tail).
__global__ __launch_bounds__(256, 2) void dense_yb(
    const float* __restrict__ x,      // [N,64]
    const float* __restrict__ W,      // [64,128]
    const float* __restrict__ bias,   // [64]
    signed char* __restrict__ Y8,     // [N,64] i8 out
    float* __restrict__ scale,        // [N] fp32 out (rowmax/127)
    unsigned short* __restrict__ Bb,  // [N,64] bf16 out
    int n_groups, int n_nodes)
{
    const int lane = threadIdx.x & 63;
    const int wave = threadIdx.x >> 6;
    const int col  = lane & 15;
    const int quad = lane >> 4;
    int group = blockIdx.x * WPB + wave;
    if (group >= n_groups) group = n_groups - 1;  // dup work, identical writes
    const int node0 = group * 16;

    // W fragments (in-wave build; W is 32KB, L1/L2-hot)
    s16x8 bd[4][2], b2[4][2];
    #pragma unroll
    for (int nt = 0; nt < 4; ++nt) {
        const float* wrow = W + (nt * 16 + col) * (2 * C);
        #pragma unroll
        for (int ks = 0; ks < 2; ++ks) {
            const int k0 = ks * 32 + quad * 8;
            f32x4 w1a = *(const f32x4*)(wrow + k0);
            f32x4 w1b = *(const f32x4*)(wrow + k0 + 4);
            f32x4 w2a = *(const f32x4*)(wrow + C + k0);
            f32x4 w2b = *(const f32x4*)(wrow + C + k0 + 4);
            b2[nt][ks] = cvt_frag(w2a, w2b);
            f32x4 da, db;
            #pragma unroll
            for (int j = 0; j < 4; ++j) { da[j] = w1a[j] - w2a[j]; db[j] = w1b[j] - w2b[j]; }
            bd[nt][ks] = cvt_frag(da, db);
        }
    }

    // A fragments: rows node0..node0+15 (clamp-consistent at tail)
    int arow = node0 + col;
    if (arow >= n_nodes) arow = n_nodes - 1;
    const float* xp = x + (size_t)arow * C + quad * 8;
    s16x8 xi0 = cvt_frag(*(const f32x4*)xp, *(const f32x4*)(xp + 4));
    s16x8 xi1 = cvt_frag(*(const f32x4*)(xp + 32), *(const f32x4*)(xp + 36));

    f32x4 yD[4], bD[4];
    #pragma unroll
    for (int nt = 0; nt < 4; ++nt) {
        float bv = bias[nt * 16 + col];
        bD[nt] = (f32x4){bv, bv, bv, bv};
        yD[nt] = (f32x4){0.f, 0.f, 0.f, 0.f};
    }
    #pragma unroll
    for (int nt = 0; nt < 4; ++nt) {
        yD[nt] = __builtin_amdgcn_mfma_f32_16x16x32_bf16(xi0, b2[nt][0], yD[nt], 0, 0, 0);
        yD[nt] = __builtin_amdgcn_mfma_f32_16x16x32_bf16(xi1, b2[nt][1], yD[nt], 0, 0, 0);
        bD[nt] = __builtin_amdgcn_mfma_f32_16x16x32_bf16(xi0, bd[nt][0], bD[nt], 0, 0, 0);
        bD[nt] = __builtin_amdgcn_mfma_f32_16x16x32_bf16(xi1, bd[nt][1], bD[nt], 0, 0, 0);
    }

    // D layout: row = quad*4 + r (global node0+..), col = nt*16 + col.
    #pragma unroll
    for (int r = 0; r < 4; ++r) {
        int row = node0 + quad * 4 + r;
        if (row >= n_nodes) row = n_nodes - 1;  // dup store, same value (see A clamp)
        // per-row max|y|: in-lane over nt, then across the 16 lanes of this quad
        float am = fmaxf(fmaxf(fabsf(yD[0][r]), fabsf(yD[1][r])),
                         fmaxf(fabsf(yD[2][r]), fabsf(yD[3][r])));
        am = fmaxf(am, __shfl_xor(am, 1));
        am = fmaxf(am, __shfl_xor(am, 2));
        am = fmaxf(am, __shfl_xor(am, 4));
        am = fmaxf(am, __shfl_xor(am, 8));
        const float inv = am > 0.f ? 127.0f / am : 0.f;
        #pragma unroll
        for (int nt = 0; nt < 4; ++nt) {
            int q = __float2int_rn(yD[nt][r] * inv);
            q = q > 127 ? 127 : (q < -127 ? -127 : q);
            Y8[(size_t)row * C + nt * 16 + col] = (signed char)q;
            Bb[(size_t)row * C + nt * 16 + col] =
                (unsigned short)(pk2(bD[nt][r], 0.f) & 0xFFFF);
        }
        if (col == 0) scale[row] = am * (1.0f / 127.0f);
    }
}

// ---- kernel 2: out[i] = relu(Bb_i + max_e scale[j_e] * Y8[j_e]) ----
// One wave per node; lane = channel. Gather target (Y8+scale = 3.4MB) is
// L2-resident per XCD. 16 independent 64B line gathers + broadcast scales.
__global__ __launch_bounds__(256, 6) void gathermax(
    const signed char* __restrict__ Y8,    // [N,64] i8
    const float* __restrict__ scale,       // [N]
    const unsigned short* __restrict__ Bb, // [N,64] bf16
    const int* __restrict__ src,           // [E]
    float* __restrict__ out,               // [N,64]
    int n_nodes)
{
    const int lane = threadIdx.x & 63;
    const int wave = threadIdx.x >> 6;
    int i = blockIdx.x * WPB + wave;
    if (i >= n_nodes) i = n_nodes - 1;  // dup work, identical writes

    int jreg = 0;
    if (lane < DEG) jreg = src[i * DEG + lane];

    float bs = bf2f(Bb[(size_t)i * C + lane]);  // independent, issued early

    // broadcast indices, issue all 16 gathers (i8 line + scalar scale)
    signed char v[DEG];
    float sc[DEG];
    #pragma unroll
    for (int e = 0; e < DEG; ++e) {
        int j = __shfl(jreg, e);
        v[e]  = Y8[(size_t)j * C + lane];  // 64 lanes x 1B = 64B line
        sc[e] = scale[j];                  // same addr all lanes -> broadcast
    }

    float m = (float)v[0] * sc[0];
    #pragma unroll
    for (int e = 1; e < DEG; ++e) m = fmaxf(m, (float)v[e] * sc[e]);

    out[(size_t)i * C + lane] = fmaxf(bs + m, 0.0f);
}

// ---- fallback (ws too small): R6-class fused kernel, fp32 gather ----
__global__ __launch_bounds__(256, 2) void edgeconv_fallback(
    const float* __restrict__ x, const int* __restrict__ src,
    const float* __restrict__ W, const float* __restrict__ bias,
    float* __restrict__ out, int n_groups)
{
    const int lane = threadIdx.x & 63, wave = threadIdx.x >> 6;
    const int col = lane & 15, quad = lane >> 4;
    int group = blockIdx.x * WPB + wave;
    if (group >= n_groups) group = n_groups - 1;

    auto frag = [&](int row, int koff) {
        const float* p = x + row * C + koff;
        return cvt_frag(*(const f32x4*)p, *(const f32x4*)(p + 4));
    };

    s16x8 b2[4][2];
    f32x4 baseD[4];
    {
        s16x8 bd[4][2];
        #pragma unroll
        for (int nt = 0; nt < 4; ++nt) {
            const float* wrow = W + (nt * 16 + col) * (2 * C);
            #pragma unroll
            for (int ks = 0; ks < 2; ++ks) {
                const int k0 = ks * 32 + quad * 8;
                f32x4 w1a = *(const f32x4*)(wrow + k0);
                f32x4 w1b = *(const f32x4*)(wrow + k0 + 4);
                f32x4 w2a = *(const f32x4*)(wrow + C + k0);
                f32x4 w2b = *(const f32x4*)(wrow + C + k0 + 4);
                b2[nt][ks] = cvt_frag(w2a, w2b);
                f32x4 da, db;
                #pragma unroll
                for (int j = 0; j < 4; ++j) { da[j] = w1a[j] - w2a[j]; db[j] = w1b[j] - w2b[j]; }
                bd[nt][ks] = cvt_frag(da, db);
            }
        }
        #pragma unroll
        for (int nt = 0; nt < 4; ++nt) {
            float bv = bias[nt * 16 + col];
            baseD[nt] = (f32x4){bv, bv, bv, bv};
        }
        const int nrow = group * 16 + col;
        s16x8 xi0 = frag(nrow, quad * 8), xi1 = frag(nrow, 32 + quad * 8);
        #pragma unroll
        for (int nt = 0; nt < 4; ++nt) {
            baseD[nt] = __builtin_amdgcn_mfma_f32_16x16x32_bf16(xi0, bd[nt][0], baseD[nt], 0, 0, 0);
            baseD[nt] = __builtin_amdgcn_mfma_f32_16x16x32_bf16(xi1, bd[nt][1], baseD[nt], 0, 0, 0);
        }
    }
    int idx[16];
    #pragma unroll
    for (int n = 0; n < 16; ++n) idx[n] = src[group * 256 + n * DEG + col];
    s16x8 xa[3][2];
    #pragma unroll
    for (int p = 0; p < 2; ++p) {
        xa[p][0] = frag(idx[p], quad * 8); xa[p][1] = frag(idx[p], 32 + quad * 8);
    }
    #pragma unroll
    for (int n = 0; n < 16; ++n) {
        if (n + 2 < 16) {
            xa[(n + 2) % 3][0] = frag(idx[n + 2], quad * 8);
            xa[(n + 2) % 3][1] = frag(idx[n + 2], 32 + quad * 8);
        }
        const int slane = ((n >> 2) << 4) | col;
        f32x4 acc[4];
        #pragma unroll
        for (int nt = 0; nt < 4; ++nt) {
            float bb = __shfl(baseD[nt][n & 3], slane);
            acc[nt] = (f32x4){bb, bb, bb, bb};
        }
        #pragma unroll
        for (int nt = 0; nt < 4; ++nt) {
            acc[nt] = __builtin_amdgcn_mfma_f32_16x16x32_bf16(xa[n % 3][0], b2[nt][0], acc[nt], 0, 0, 0);
            acc[nt] = __builtin_amdgcn_mfma_f32_16x16x32_bf16(xa[n % 3][1], b2[nt][1], acc[nt], 0, 0, 0);
        }
        float m[4];
        #pragma unroll
        for (int nt = 0; nt < 4; ++nt) {
            float t = fmaxf(fmaxf(acc[nt][0], acc[nt][1]),
                            fmaxf(acc[nt][2], acc[nt][3]));
            t = fmaxf(t, __shfl_xor(t, 16));
            t = fmaxf(t, __shfl_xor(t, 32));
            m[nt] = t;
        }
        float r = quad == 0 ? m[0] : quad == 1 ? m[1] : quad == 2 ? m[2] : m[3];
        out[(group * 16 + n) * C + lane] = fmaxf(r, 0.0f);
    }
}

extern "C" void kernel_launch(void* const* d_in, const int* in_sizes, int n_in,
                              void* d_out, int out_size, void* d_ws, size_t ws_size,
                              hipStream_t stream) {
    const float* x    = (const float*)d_in[0];
    const int*   src  = (const int*)  d_in[1];   // row 0 of edge_index
    const float* W    = (const float*)d_in[3];
    const float* b    = (const float*)d_in[4];
    float*       out  = (float*)d_out;

    const int n_nodes = in_sizes[0] / C;  // 50000

    // ws: [ Y8 i8 : N*C ][ scale f32 : N ][ Bb bf16 : N*C ]
    const size_t y8_bytes = (size_t)n_nodes * C;                      // 3.2 MB
    const size_t sc_bytes = (size_t)n_nodes * sizeof(float);          // 0.2 MB
    const size_t bb_bytes = (size_t)n_nodes * C * sizeof(unsigned short); // 6.4 MB

    if (ws_size >= y8_bytes + sc_bytes + bb_bytes) {
        signed char*    Y8 = (signed char*)d_ws;
        float*          SC = (float*)((char*)d_ws + y8_bytes);
        unsigned short* Bb = (unsigned short*)((char*)d_ws + y8_bytes + sc_bytes);
        const int n_groups = (n_nodes + 15) / 16;            // 3125
        dense_yb<<<(n_groups + WPB - 1) / WPB, 256, 0, stream>>>(
            x, W, b, Y8, SC, Bb, n_groups, n_nodes);
        gathermax<<<(n_nodes + WPB - 1) / WPB, 256, 0, stream>>>(
            Y8, SC, Bb, src, out, n_nodes);
    } else {
        const int n_groups = (n_nodes + 15) / 16;
        edgeconv_fallback<<<(n_groups + WPB - 1) / WPB, 256, 0, stream>>>(
            x, src, W, b, out, n_groups);
    }
}